// Round 1
// baseline (417.067 us; speedup 1.0000x reference)
//
#include <hip/hip_runtime.h>

namespace {

constexpr int Wd = 160;
constexpr int Hd = 192;
constexpr int Dd = 160;
constexpr int NBATCH = 2;
constexpr int TX = 16;
constexpr int TY = 16;
constexpr int CZ = 40;            // z-chunk depth per block
constexpr int XSTR = 12;          // xs inner stride: 5 fields padded to 12 (16B-aligned, bank-friendly)
constexpr int NPARTS = (Wd / TX) * (Hd / TY) * NBATCH * (Dd / CZ);  // 10*12*8 = 960
constexpr float KSIZE = 729.0f;
constexpr float INV_KSIZE = 1.0f / 729.0f;

// Fields: 0=I*I, 1=I*T, 2=T*T, 3=I, 4=T   (T pre-scaled to (t+1)*0.5; zero-pad applies AFTER scaling)

__global__ __launch_bounds__(256, 2)
void ncc_main(const float* __restrict__ inp, const float* __restrict__ tgt,
              float* __restrict__ partials)
{
    __shared__ float xs[24 * 16 * XSTR];   // 18432 B: x-summed 5-field plane, rows y0-4..y0+19
    __shared__ float ring[5 * 9 * 256];    // 46080 B: z-ring of 2D sums, per-thread slots

    const int tid = threadIdx.x;
    const int n  = blockIdx.z >> 2;
    const int zc = blockIdx.z & 3;
    const int x0 = blockIdx.x * TX;
    const int y0 = blockIdx.y * TY;
    const int z0 = zc * CZ;

    // zero the ring (each thread only ever touches its own tid-slots; no sync needed)
    #pragma unroll
    for (int i = 0; i < 45; ++i) ring[i * 256 + tid] = 0.0f;

    // ---- Phase-1 job decode: 240 threads = (row 0..23) x (half 0..1) x (field 0..4) ----
    const int f = tid % 5;
    const int j = tid / 5;              // 0..51, valid < 48
    const int r = j >> 1;               // row in 24-row halo band
    const int h = j & 1;                // which 8-wide output half
    const bool p1a = (tid < 240);
    const int gy  = y0 - 4 + r;
    const int gxb = x0 - 4 + 8 * h;     // multiple of 4 -> float4-aligned
    const bool yok = (gy >= 0) && (gy < Hd);
    bool cval[4];
    #pragma unroll
    for (int c = 0; c < 4; ++c) {
        const int gxc = gxb + 4 * c;    // OOB chunks are always fully OOB (alignment argument)
        cval[c] = yok && (gxc >= 0) && (gxc < Wd);
    }
    const bool uIsI  = (f == 0) || (f == 1) || (f == 3);
    const int  vmode = (f == 0) ? 0 : ((f <= 2) ? 1 : 2);   // 0: *I, 1: *T, 2: *1
    const int  nbase = n * (Dd * Hd * Wd);

    // ---- Phase-2 decode: one output column (yi, xi) per thread ----
    const int yi = tid >> 4;
    const int xi = tid & 15;

    float S0 = 0.f, S1 = 0.f, S2 = 0.f, S3 = 0.f, S4 = 0.f;  // running z-window sums
    float acc = 0.f;

    for (int t = 0; t < CZ + 8; ++t) {
        const int zi = z0 - 4 + t;
        const bool zok = (zi >= 0) && (zi < Dd);   // block-uniform

        __syncthreads();   // xs free to overwrite (prev P2 done)

        if (zok && p1a) {
            const int rowoff = nbase + (zi * Hd + gy) * Wd + gxb;
            const float4* pI = reinterpret_cast<const float4*>(inp + rowoff);
            const float4* pT = reinterpret_cast<const float4*>(tgt + rowoff);
            float iv[16], tv[16];
            #pragma unroll
            for (int c = 0; c < 4; ++c) {
                float4 a = make_float4(0.f, 0.f, 0.f, 0.f);
                float4 b = make_float4(0.f, 0.f, 0.f, 0.f);
                if (cval[c]) {
                    a = pI[c];
                    float4 braw = pT[c];
                    b.x = (braw.x + 1.0f) * 0.5f;
                    b.y = (braw.y + 1.0f) * 0.5f;
                    b.z = (braw.z + 1.0f) * 0.5f;
                    b.w = (braw.w + 1.0f) * 0.5f;
                }
                iv[4*c+0] = a.x; iv[4*c+1] = a.y; iv[4*c+2] = a.z; iv[4*c+3] = a.w;
                tv[4*c+0] = b.x; tv[4*c+1] = b.y; tv[4*c+2] = b.z; tv[4*c+3] = b.w;
            }
            float p[16];
            #pragma unroll
            for (int q = 0; q < 16; ++q) {
                const float u = uIsI ? iv[q] : tv[q];
                const float v = (vmode == 0) ? iv[q] : ((vmode == 1) ? tv[q] : 1.0f);
                p[q] = u * v;
            }
            // sliding 9-window along x -> 8 outputs
            float s = 0.f;
            #pragma unroll
            for (int q = 0; q < 9; ++q) s += p[q];
            float o[8];
            o[0] = s;
            #pragma unroll
            for (int k = 1; k < 8; ++k) { s += p[k + 8] - p[k - 1]; o[k] = s; }
            // store with per-lane rotation to spread LDS banks
            #pragma unroll
            for (int kk = 0; kk < 8; ++kk) {
                const int k = (kk + j) & 7;
                xs[(r * 16 + 8 * h + k) * XSTR + f] = o[k];
            }
        }

        __syncthreads();   // xs plane ready

        float a0 = 0.f, a1 = 0.f, a2 = 0.f, a3 = 0.f, a4 = 0.f;
        if (zok) {
            #pragma unroll
            for (int k = 0; k < 9; ++k) {
                const float* b = &xs[((yi + k) * 16 + xi) * XSTR];
                const float4 v = *reinterpret_cast<const float4*>(b);
                a0 += v.x; a1 += v.y; a2 += v.z; a3 += v.w; a4 += b[4];
            }
        }

        const int slot = t % 9;
        float* rp = &ring[slot * 256 + tid];
        S0 += a0 - rp[0 * 9 * 256]; rp[0 * 9 * 256] = a0;
        S1 += a1 - rp[1 * 9 * 256]; rp[1 * 9 * 256] = a1;
        S2 += a2 - rp[2 * 9 * 256]; rp[2 * 9 * 256] = a2;
        S3 += a3 - rp[3 * 9 * 256]; rp[3 * 9 * 256] = a3;
        S4 += a4 - rp[4 * 9 * 256]; rp[4 * 9 * 256] = a4;

        if (t >= 8) {   // output voxel z = z0 + t - 8 now has its full (clipped) window
            const float sii = S0, sit = S1, stt = S2, si = S3, st = S4;
            const float Ihat = si * INV_KSIZE;
            const float That = st * INV_KSIZE;
            const float cross = sit - Ihat * st - That * si + That * Ihat * KSIZE;
            const float tvar  = stt - 2.0f * That * st + That * That * KSIZE;
            const float ivar  = sii - 2.0f * Ihat * si + Ihat * Ihat * KSIZE;
            acc += (cross * cross) / (tvar * ivar + 1e-5f);
        }
    }

    // ---- block reduction of acc ----
    #pragma unroll
    for (int off = 32; off > 0; off >>= 1) acc += __shfl_down(acc, off, 64);
    __syncthreads();                      // xs reuse: last P2 readers done
    if ((tid & 63) == 0) xs[tid >> 6] = acc;
    __syncthreads();
    if (tid == 0) {
        const float tot = xs[0] + xs[1] + xs[2] + xs[3];
        partials[(blockIdx.z * gridDim.y + blockIdx.y) * gridDim.x + blockIdx.x] = tot;
    }
}

__global__ void ncc_finalize(const float* __restrict__ partials, float* __restrict__ out)
{
    __shared__ double red[256];
    double s = 0.0;
    for (int i = threadIdx.x; i < NPARTS; i += 256) s += (double)partials[i];
    red[threadIdx.x] = s;
    __syncthreads();
    for (int off = 128; off > 0; off >>= 1) {
        if (threadIdx.x < (unsigned)off) red[threadIdx.x] += red[threadIdx.x + off];
        __syncthreads();
    }
    if (threadIdx.x == 0) {
        const double total_elems = (double)NBATCH * Dd * Hd * Wd;  // 9830400
        out[0] = (float)(-red[0] / total_elems);
    }
}

} // namespace

extern "C" void kernel_launch(void* const* d_in, const int* in_sizes, int n_in,
                              void* d_out, int out_size, void* d_ws, size_t ws_size,
                              hipStream_t stream)
{
    const float* inp = (const float*)d_in[0];
    const float* tgt = (const float*)d_in[1];
    float* out = (float*)d_out;
    float* partials = (float*)d_ws;   // 960 floats

    dim3 grid(Wd / TX, Hd / TY, NBATCH * (Dd / CZ));   // (10, 12, 8)
    ncc_main<<<grid, 256, 0, stream>>>(inp, tgt, partials);
    ncc_finalize<<<1, 256, 0, stream>>>(partials, out);
}

// Round 2
// 284.066 us; speedup vs baseline: 1.4682x; 1.4682x over previous
//
#include <hip/hip_runtime.h>

namespace {

constexpr int Wd = 160;
constexpr int Hd = 192;
constexpr int Dd = 160;
constexpr int TX = 16;
constexpr int TY = 16;
constexpr int CZ = 40;                    // z-chunk depth per block (4 chunks over Dd)
constexpr float INV_K = 1.0f / 729.0f;
constexpr float INV_TOT = 1.0f / 9830400.0f;   // 2*160*192*160

// Fields: xs4 = {II, IT, TT, I} as float4; xsT = {T}. T pre-scaled (t+1)*0.5,
// zero padding applied AFTER scaling (pad contributes 0 to every sum).

__global__ __launch_bounds__(256, 4)
void ncc_main(const float* __restrict__ inp, const float* __restrict__ tgt,
              float* __restrict__ out)
{
    __shared__ float4 xs4[24 * 16];   // 6144 B, x-summed II,IT,TT,I plane (rows y0-4..y0+19)
    __shared__ float  xsT[24 * 16];   // 1536 B, x-summed T plane
    __shared__ float  red[4];

    const int tid = threadIdx.x;
    const int n  = (int)blockIdx.z >> 2;
    const int zc = (int)blockIdx.z & 3;
    const int x0 = blockIdx.x * TX;
    const int y0 = blockIdx.y * TY;
    const int z0 = zc * CZ;

    // ---- phase-1 decode: 240 threads = (row 0..23) x (half 0..1) x (field 0..4)
    const int f = tid % 5;
    const int j = tid / 5;                    // 0..51, active j<48
    const bool p1a = (tid < 240);
    const int gy  = y0 - 4 + (j >> 1);
    const int gxb = x0 - 4 + 8 * (j & 1);     // float4-aligned
    const bool yok = (gy >= 0) && (gy < Hd);
    bool cval[4];
    #pragma unroll
    for (int c = 0; c < 4; ++c) {
        const int gx = gxb + 4 * c;           // OOB chunks are fully OOB (alignment)
        cval[c] = p1a && yok && (gx >= 0) && (gx < Wd);
    }
    const bool uIsI = (f == 0) || (f == 1) || (f == 3);
    const int  vmode = (f == 0) ? 0 : ((f <= 2) ? 1 : 2);   // *I, *T, *1
    float* sbase; int smul;
    if (f < 4) { sbase = ((float*)xs4) + f; smul = 4; }
    else       { sbase = xsT;               smul = 1; }
    const int rbase = n * (Dd * Hd * Wd) + gy * Wd + gxb;

    // ---- phase-2 decode: one output column (yi, xi)
    const int yi = tid >> 4;
    const int xi = tid & 15;
    const float4* prow4 = &xs4[yi * 16 + xi];
    const float*  prowT = &xsT[yi * 16 + xi];

    float rng[5][9];                           // z-ring in REGISTERS (slot = s%9, static after unroll)
    #pragma unroll
    for (int a = 0; a < 5; ++a)
        #pragma unroll
        for (int b = 0; b < 9; ++b) rng[a][b] = 0.f;
    float S[5] = {0.f, 0.f, 0.f, 0.f, 0.f};
    float acc = 0.f;

    for (int tb = 0; tb < 54; tb += 9) {       // 48 live slices, padded to 54 for unroll-by-9
        #pragma unroll
        for (int u = 0; u < 9; ++u) {
            const int s = tb + u;              // slice index; zi = z0-4+s
            const bool live = (s < 48);        // block-uniform
            const int zi = z0 - 4 + s;
            const bool zok = live && (zi >= 0) && (zi < Dd);

            __syncthreads();                   // xs planes free (prev phase-2 done)

            if (zok && p1a) {
                const float* pI = inp + (rbase + zi * (Hd * Wd));
                const float* pT = tgt + (rbase + zi * (Hd * Wd));
                float iv[16], tv[16];
                #pragma unroll
                for (int c = 0; c < 4; ++c) {
                    float4 a4 = make_float4(0.f, 0.f, 0.f, 0.f);
                    float4 b4 = make_float4(0.f, 0.f, 0.f, 0.f);
                    if (cval[c]) {
                        a4 = *reinterpret_cast<const float4*>(pI + 4 * c);
                        const float4 br = *reinterpret_cast<const float4*>(pT + 4 * c);
                        b4.x = (br.x + 1.f) * 0.5f; b4.y = (br.y + 1.f) * 0.5f;
                        b4.z = (br.z + 1.f) * 0.5f; b4.w = (br.w + 1.f) * 0.5f;
                    }
                    iv[4*c+0] = a4.x; iv[4*c+1] = a4.y; iv[4*c+2] = a4.z; iv[4*c+3] = a4.w;
                    tv[4*c+0] = b4.x; tv[4*c+1] = b4.y; tv[4*c+2] = b4.z; tv[4*c+3] = b4.w;
                }
                float p[16];
                #pragma unroll
                for (int q = 0; q < 16; ++q) {
                    const float uu = uIsI ? iv[q] : tv[q];
                    const float vv = (vmode == 0) ? iv[q] : ((vmode == 1) ? tv[q] : 1.0f);
                    p[q] = uu * vv;
                }
                float ssum = 0.f;
                #pragma unroll
                for (int q = 0; q < 9; ++q) ssum += p[q];
                float o[8];
                o[0] = ssum;
                #pragma unroll
                for (int k = 1; k < 8; ++k) { ssum += p[k + 8] - p[k - 1]; o[k] = ssum; }
                // per-lane rotation spreads banks for the scalar stores (~2-way max)
                #pragma unroll
                for (int kk = 0; kk < 8; ++kk) {
                    const int k = (kk + j) & 7;
                    sbase[(8 * j + k) * smul] = o[k];
                }
            }

            __syncthreads();                   // xs planes ready

            if (live) {
                float a0 = 0.f, a1 = 0.f, a2 = 0.f, a3 = 0.f, a4v = 0.f;
                if (zok) {                     // pad slices contribute 0
                    #pragma unroll
                    for (int k = 0; k < 9; ++k) {
                        const float4 v = prow4[16 * k];   // conflict-free b128
                        a0 += v.x; a1 += v.y; a2 += v.z; a3 += v.w;
                        a4v += prowT[16 * k];             // 2-way = free
                    }
                }
                const float av[5] = {a0, a1, a2, a3, a4v};
                #pragma unroll
                for (int ff = 0; ff < 5; ++ff) { S[ff] += av[ff] - rng[ff][u]; rng[ff][u] = av[ff]; }
                if (s >= 8) {                  // output voxel z = z0 + s - 8
                    const float sii = S[0], sit = S[1], stt = S[2], si = S[3], st = S[4];
                    const float cross = sit - si * st * INV_K;
                    const float tvar  = stt - st * st * INV_K;
                    const float ivar  = sii - si * si * INV_K;
                    acc += cross * cross * __builtin_amdgcn_rcpf(tvar * ivar + 1e-5f);
                }
            }
        }
    }

    // ---- block reduction, fused finalize via one atomic per block
    #pragma unroll
    for (int off = 32; off > 0; off >>= 1) acc += __shfl_down(acc, off, 64);
    if ((tid & 63) == 0) red[tid >> 6] = acc;
    __syncthreads();
    if (tid == 0) {
        const float tot = red[0] + red[1] + red[2] + red[3];
        atomicAdd(out, -tot * INV_TOT);
    }
}

} // namespace

extern "C" void kernel_launch(void* const* d_in, const int* in_sizes, int n_in,
                              void* d_out, int out_size, void* d_ws, size_t ws_size,
                              hipStream_t stream)
{
    const float* inp = (const float*)d_in[0];
    const float* tgt = (const float*)d_in[1];
    float* out = (float*)d_out;

    hipMemsetAsync(d_out, 0, sizeof(float), stream);   // d_out is re-poisoned to 0xAA each call
    dim3 grid(Wd / TX, Hd / TY, 2 * (Dd / CZ));        // (10, 12, 8) = 960 blocks <= 1024 slots
    ncc_main<<<grid, 256, 0, stream>>>(inp, tgt, out);
}

// Round 3
// 238.707 us; speedup vs baseline: 1.7472x; 1.1900x over previous
//
#include <hip/hip_runtime.h>

namespace {

constexpr int Wd = 160, Hd = 192, Dd = 160;
constexpr int TX = 16, TY = 16, CZ = 40;
constexpr int HW = Hd * Wd;
constexpr float INV_K = 1.0f / 729.0f;
constexpr float INV_TOT = 1.0f / 9830400.0f;   // 2*160*192*160
constexpr int R4 = 17;     // xs4 row stride in float4 (16 cols + 1 pad -> <=2-way banks)
constexpr int RT = 69;     // xsT row stride in floats (cols at 4*c, +1 pad -> <=2-way banks)
constexpr int ROWS = 26;   // 24 halo rows + 2 pad rows absorbing lanes 240..255

// Fields by f: 0=II(.x) 1=IT(.y) 2=TT(.z) 3=I(.w) 4=T(xsT). T scaled (t+1)*0.5,
// zero padding applied AFTER scaling (OOB mask folded into uu coefficients).

__global__ __launch_bounds__(256, 4)
void ncc_main(const float* __restrict__ inp, const float* __restrict__ tgt,
              float* __restrict__ out)
{
    __shared__ float4 xs4[2][ROWS * R4];   // 2 x 7072 B
    __shared__ float  xsT[2][ROWS * RT];   // 2 x 7176 B
    __shared__ float  red[4];

    const int tid = threadIdx.x;
    const int n  = (int)blockIdx.z >> 2;
    const int zc = (int)blockIdx.z & 3;
    const int x0 = blockIdx.x * TX, y0 = blockIdx.y * TY, z0 = zc * CZ;

    // ---- phase-1 decode: (row r 0..23) x (half h) x (field f); lanes>=240 -> masked, pad rows
    const int f = tid % 5;
    const int j = tid / 5;
    const int r = j >> 1, h = j & 1;
    const int gy = y0 - 4 + r;
    const bool yok = (tid < 240) && (gy >= 0) && (gy < Hd);
    const int gyc = min(max(gy, 0), Hd - 1);
    const int gxb = x0 - 4 + 8 * h;
    const bool uI = (f == 0) || (f == 1) || (f == 3);
    const float bI = (f == 0) ? 1.f : 0.f;
    const float bT = (f == 1 || f == 2) ? 0.5f : 0.f;
    const float bC = (f == 1 || f == 2) ? 0.5f : ((f >= 3) ? 1.f : 0.f);
    float aI[4], aTC[4];
    int voff[4];
    #pragma unroll
    for (int c = 0; c < 4; ++c) {
        const int gx = gxb + 4 * c;                       // OOB chunks fully OOB (alignment)
        const float m = (yok && gx >= 0 && gx < Wd) ? 1.f : 0.f;
        const int gxc = min(max(gx, 0), Wd - 4);          // clamped, stays 16B-aligned
        voff[c] = gyc * Wd + gxc;                         // static per-lane; z via uniform base
        aI[c]  = uI ? m : 0.f;
        aTC[c] = uI ? 0.f : 0.5f * m;
    }
    const long long nb = (long long)n * ((long long)Dd * HW);
    const float* baseI = inp + nb;
    const float* baseT = tgt + nb;

    // store bases per plane parity; all stores use static imm offsets 16B*k
    const int stoff = (f < 4) ? ((r * R4 + 8 * h) * 4 + f) : (r * RT + 32 * h);
    float* const st0 = (f < 4) ? ((float*)xs4[0] + stoff) : (xsT[0] + stoff);
    float* const st1 = (f < 4) ? ((float*)xs4[1] + stoff) : (xsT[1] + stoff);

    // ---- phase-2 decode: one output column (yi, xi)
    const int yi = tid >> 4, xi = tid & 15;
    const float4* const rd4_0 = &xs4[0][yi * R4 + xi];
    const float4* const rd4_1 = &xs4[1][yi * R4 + xi];
    const float*  const rdT_0 = &xsT[0][yi * RT + 4 * xi];
    const float*  const rdT_1 = &xsT[1][yi * RT + 4 * xi];

    float4 rng4[9]; float rngT[9];
    #pragma unroll
    for (int q = 0; q < 9; ++q) { rng4[q] = make_float4(0.f,0.f,0.f,0.f); rngT[q] = 0.f; }
    float4 S4 = make_float4(0.f,0.f,0.f,0.f);
    float ST = 0.f, acc = 0.f;

    float4 Ic[4], Tc[4];
    #pragma unroll
    for (int c = 0; c < 4; ++c) { Ic[c] = make_float4(0.f,0.f,0.f,0.f); Tc[c] = Ic[c]; }

    // prologue: prefetch slice s=0 (zi=z0-4); invalid only when zc==0 (then s=0..3 unused)
    if (z0 - 4 >= 0) {
        const float* pI = baseI + (long long)(z0 - 4) * HW;
        const float* pT = baseT + (long long)(z0 - 4) * HW;
        #pragma unroll
        for (int c = 0; c < 4; ++c) {
            Ic[c] = *(const float4*)(pI + voff[c]);
            Tc[c] = *(const float4*)(pT + voff[c]);
        }
    }

    for (int tb = 0; tb < 54; tb += 18) {          // 48 live slices; 18-unroll -> static slot/parity
        #pragma unroll
        for (int u = 0; u < 18; ++u) {
            const int s = tb + u;                  // block-uniform
            if (s < 48) {
                const int zi = z0 - 4 + s;
                const bool zok = (zi >= 0) && (zi < Dd);    // uniform
                const int slot = u % 9;            // static (tb % 9 == 0)
                const int pb = u & 1;              // static plane parity (tb even)
                float* const st = pb ? st1 : st0;

                // ---- phase-1: consume prefetched regs for slice s
                if (zok) {
                    float p[16];
                    #pragma unroll
                    for (int c = 0; c < 4; ++c) {
                        const float iv[4] = {Ic[c].x, Ic[c].y, Ic[c].z, Ic[c].w};
                        const float tv[4] = {Tc[c].x, Tc[c].y, Tc[c].z, Tc[c].w};
                        #pragma unroll
                        for (int q2 = 0; q2 < 4; ++q2) {
                            const float uu = fmaf(iv[q2], aI[c], fmaf(tv[q2], aTC[c], aTC[c]));
                            const float vv = fmaf(iv[q2], bI,    fmaf(tv[q2], bT,    bC));
                            p[4*c + q2] = uu * vv;
                        }
                    }
                    float ssum = 0.f;
                    #pragma unroll
                    for (int q = 0; q < 9; ++q) ssum += p[q];
                    float o[8]; o[0] = ssum;
                    #pragma unroll
                    for (int k = 1; k < 8; ++k) { ssum += p[k + 8] - p[k - 1]; o[k] = ssum; }
                    #pragma unroll
                    for (int k = 0; k < 8; ++k) st[4 * k] = o[k];   // static 16B imm offsets
                }

                // ---- prefetch slice s+1 (consumed after next barrier)
                {
                    const int zi2 = z0 - 3 + s;
                    if ((s + 1) < 48 && zi2 >= 0 && zi2 < Dd) {     // uniform
                        const float* pI = baseI + (long long)zi2 * HW;
                        const float* pT = baseT + (long long)zi2 * HW;
                        #pragma unroll
                        for (int c = 0; c < 4; ++c) {
                            Ic[c] = *(const float4*)(pI + voff[c]);
                            Tc[c] = *(const float4*)(pT + voff[c]);
                        }
                    }
                }

                __syncthreads();                   // single barrier per slice

                // ---- phase-2: y-sum from plane[pb], z-ring, cc
                float4 A = make_float4(0.f,0.f,0.f,0.f);
                float aTv = 0.f;
                if (zok) {
                    const float4* const rd4 = pb ? rd4_1 : rd4_0;
                    const float*  const rdT = pb ? rdT_1 : rdT_0;
                    #pragma unroll
                    for (int k = 0; k < 9; ++k) {
                        const float4 v = rd4[k * R4];
                        A.x += v.x; A.y += v.y; A.z += v.z; A.w += v.w;
                        aTv += rdT[k * RT];
                    }
                }
                S4.x += A.x - rng4[slot].x; S4.y += A.y - rng4[slot].y;
                S4.z += A.z - rng4[slot].z; S4.w += A.w - rng4[slot].w;
                rng4[slot] = A;
                ST += aTv - rngT[slot]; rngT[slot] = aTv;

                if (s >= 8) {                      // output voxel z = z0 + s - 8
                    const float sii = S4.x, sit = S4.y, stt = S4.z, si = S4.w, stv = ST;
                    const float cross = sit - si * stv * INV_K;
                    const float tvar  = stt - stv * stv * INV_K;
                    const float ivar  = sii - si  * si  * INV_K;
                    acc += cross * cross * __builtin_amdgcn_rcpf(tvar * ivar + 1e-5f);
                }
            }
        }
    }

    // ---- block reduction + fused finalize (one atomic per block)
    #pragma unroll
    for (int off = 32; off > 0; off >>= 1) acc += __shfl_down(acc, off, 64);
    if ((tid & 63) == 0) red[tid >> 6] = acc;
    __syncthreads();
    if (tid == 0) {
        const float tot = red[0] + red[1] + red[2] + red[3];
        atomicAdd(out, -tot * INV_TOT);
    }
}

} // namespace

extern "C" void kernel_launch(void* const* d_in, const int* in_sizes, int n_in,
                              void* d_out, int out_size, void* d_ws, size_t ws_size,
                              hipStream_t stream)
{
    const float* inp = (const float*)d_in[0];
    const float* tgt = (const float*)d_in[1];
    float* out = (float*)d_out;

    hipMemsetAsync(d_out, 0, sizeof(float), stream);   // d_out re-poisoned each call
    dim3 grid(Wd / TX, Hd / TY, 2 * (Dd / CZ));        // (10,12,8) = 960 blocks <= 1024 slots
    ncc_main<<<grid, 256, 0, stream>>>(inp, tgt, out);
}